// Round 6
// baseline (321.294 us; speedup 1.0000x reference)
//
#include <hip/hip_runtime.h>
#include <hip/hip_bf16.h>
#include <math.h>

// NetVLAD: B=16, H=W=56 (HW=3136), D=512, K=32, fp32.
// Round 6: R5 showed k_s at VALUBusy 16% even with 52% occupancy -> the
// 1 FMA : 1 SGPR-dword ratio of the inner loop is the stall source, not
// occupancy. Fixes:
//   K1 k_s    : 4 positions/thread (acc[4][8]) -> 4 FMA per Wc scalar;
//               256-pos tile, d-split S (8), 32-d chunks, reg prefetch.
//   K2 k_soft : 4 threads/pos (grid 784), sum S slabs + softmax + a_sum.
//   K3 k_ax   : d-split GEMM: grid (PS=28, ds=2, b=16) = 896 blocks,
//               16-pos chunks, 8d x 4k per thread; vpart 28 slabs (28 MB).
//   K4 k_norm1: 2048 blocks x 128 thr, 1 cell/thread, 28 indep loads,
//               row-norm via width-32 shfl (fixes 1-block/CU streaming).
//   K5 k_norm2: global L2 scale.

#define BATCH 16
#define HW    3136
#define DIM   512
#define KCL   32
#define NPOS  (BATCH * HW)     // 50176

__device__ __forceinline__ void atomAddF(float* p, float v) {
    unsafeAtomicAdd(p, v);
}

// ---------------- K1: s-partial GEMM, 4 pos/thread ----------------
// grid (196, S), block 256 = 4 waves. Block tile: 256 flat positions x 32 k,
// d-slice dwidth = 512/S. Wave wv owns k [8wv,8wv+8); lane covers positions
// {lane + 64*pi}, pi<4. Wc via wave-uniform SMEM s_loads, 4 FMAs per dword.
__global__ __launch_bounds__(256) void k_s(const float* __restrict__ x,
                                           const float* __restrict__ Wc,
                                           float* __restrict__ spart,
                                           int dwidth) {
    __shared__ float xs[256 * 36];   // 36 KB; stride 36 (16B-aligned rows)
    const int t    = threadIdx.x;
    const int lane = t & 63;
    const int wv   = t >> 6;
    const int k0   = __builtin_amdgcn_readfirstlane(wv * 8);
    const int n0   = blockIdx.x * 256;           // flat position base
    const int d0   = blockIdx.y * dwidth;

    const int sp  = t >> 3;          // staging row-within-group 0..31
    const int sc4 = (t & 7) * 4;     // staging col 0..28

    float4 px[8];
#pragma unroll
    for (int i = 0; i < 8; ++i)
        px[i] = *(const float4*)(x + ((size_t)(n0 + i * 32 + sp) * DIM + d0 + sc4));

    float acc[4][8];
#pragma unroll
    for (int pi = 0; pi < 4; ++pi)
#pragma unroll
        for (int j = 0; j < 8; ++j) acc[pi][j] = 0.f;

    for (int dc = 0; dc < dwidth; dc += 32) {
        __syncthreads();
#pragma unroll
        for (int i = 0; i < 8; ++i)
            *(float4*)&xs[(i * 32 + sp) * 36 + sc4] = px[i];
        __syncthreads();
        if (dc + 32 < dwidth) {      // prefetch next chunk during compute
#pragma unroll
            for (int i = 0; i < 8; ++i)
                px[i] = *(const float4*)(x + ((size_t)(n0 + i * 32 + sp) * DIM + d0 + dc + 32 + sc4));
        }
        const float* wrow = Wc + (size_t)(d0 + dc) * KCL;   // uniform -> s_load
#pragma unroll
        for (int q = 0; q < 8; ++q) {
            float xv[4][4];
#pragma unroll
            for (int pi = 0; pi < 4; ++pi) {
                float4 v = *(const float4*)&xs[(pi * 64 + lane) * 36 + q * 4];
                xv[pi][0] = v.x; xv[pi][1] = v.y; xv[pi][2] = v.z; xv[pi][3] = v.w;
            }
#pragma unroll
            for (int i = 0; i < 4; ++i) {
#pragma unroll
                for (int pi = 0; pi < 4; ++pi) {
#pragma unroll
                    for (int j = 0; j < 8; ++j)
                        acc[pi][j] = fmaf(xv[pi][i], wrow[(q * 4 + i) * KCL + k0 + j], acc[pi][j]);
                }
            }
        }
    }

    // repack through LDS (reuse xs, stride 36) for coalesced slab stores
    __syncthreads();
#pragma unroll
    for (int pi = 0; pi < 4; ++pi) {
        float* r = &xs[(pi * 64 + lane) * 36 + k0];
        *(float4*)(r)     = make_float4(acc[pi][0], acc[pi][1], acc[pi][2], acc[pi][3]);
        *(float4*)(r + 4) = make_float4(acc[pi][4], acc[pi][5], acc[pi][6], acc[pi][7]);
    }
    __syncthreads();
    float* so = spart + (size_t)blockIdx.y * NPOS * KCL;
#pragma unroll
    for (int i = 0; i < 8; ++i) {
        int pos = i * 32 + sp;
        *(float4*)(so + (size_t)(n0 + pos) * KCL + sc4) = *(const float4*)&xs[pos * 36 + sc4];
    }
}

// ---------------- K2: sum S slabs + softmax ----------------
// grid 784, block 256: 4 threads per position (8 k each).
__global__ __launch_bounds__(256) void k_soft(const float* __restrict__ spart,
                                              float* __restrict__ a,
                                              float* __restrict__ a_sum, int S) {
    const int idx = blockIdx.x * 256 + threadIdx.x;
    const int n  = idx >> 2;         // position
    const int kg = idx & 3;          // k-group: k = kg*8 .. +8
    const int b  = n / HW;           // wave-uniform (16 | 3136)
    const int t  = threadIdx.x;

    float s[8];
    {
        float4 v0 = *(const float4*)(spart + ((size_t)n * KCL + kg * 8));
        float4 v1 = *(const float4*)(spart + ((size_t)n * KCL + kg * 8 + 4));
        s[0]=v0.x; s[1]=v0.y; s[2]=v0.z; s[3]=v0.w;
        s[4]=v1.x; s[5]=v1.y; s[6]=v1.z; s[7]=v1.w;
    }
    for (int sl = 1; sl < S; ++sl) {
        const float* sp = spart + (size_t)sl * NPOS * KCL + (size_t)n * KCL + kg * 8;
        float4 v0 = *(const float4*)(sp);
        float4 v1 = *(const float4*)(sp + 4);
        s[0]+=v0.x; s[1]+=v0.y; s[2]+=v0.z; s[3]+=v0.w;
        s[4]+=v1.x; s[5]+=v1.y; s[6]+=v1.z; s[7]+=v1.w;
    }

    float m = s[0];
#pragma unroll
    for (int j = 1; j < 8; ++j) m = fmaxf(m, s[j]);
    m = fmaxf(m, __shfl_xor(m, 1));
    m = fmaxf(m, __shfl_xor(m, 2));
    float sum = 0.f;
#pragma unroll
    for (int j = 0; j < 8; ++j) { s[j] = __expf(s[j] - m); sum += s[j]; }
    sum += __shfl_xor(sum, 1);
    sum += __shfl_xor(sum, 2);
    float inv = 1.f / sum;
#pragma unroll
    for (int j = 0; j < 8; ++j) s[j] *= inv;

    float* ap = a + (size_t)n * KCL + kg * 8;
    *(float4*)(ap)     = make_float4(s[0], s[1], s[2], s[3]);
    *(float4*)(ap + 4) = make_float4(s[4], s[5], s[6], s[7]);

    // a_sum: reduce over the wave's 16 positions (lanes differing in bits 2-5)
#pragma unroll
    for (int j = 0; j < 8; ++j) {
        float v = s[j];
        v += __shfl_xor(v, 4);  v += __shfl_xor(v, 8);
        v += __shfl_xor(v, 16); v += __shfl_xor(v, 32);
        s[j] = v;
    }
    if ((t & 63) < 4) {
#pragma unroll
        for (int j = 0; j < 8; ++j) atomAddF(&a_sum[b * KCL + kg * 8 + j], s[j]);
    }
}

// ---------------- K3: ax GEMM, d-split + pos-split ----------------
// grid (PS, 2, 16), block 256. Block (ps, ds, b): 256-d slice, PP=3136/PS
// positions in chunks of 16. Thread: 8 d x 4 k tile. Reg prefetch.
__global__ __launch_bounds__(256) void k_ax(const float* __restrict__ x,
                                            const float* __restrict__ a,
                                            float* __restrict__ vpart, int PP) {
    __shared__ float xs[16 * 256];   // 16 KB
    __shared__ float as_[16 * 32];   // 2 KB
    const int t  = threadIdx.x;
    const int ps = blockIdx.x;
    const int ds = blockIdx.y;
    const int b  = blockIdx.z;

    const int d0 = (t >> 3) * 8;     // 0..248 within slice
    const int k0 = (t & 7) * 4;      // 0..28
    const int dbase = ds * 256;
    const int rowb = b * HW + ps * PP;   // global position base

    const int sp  = t >> 6;          // staging pos 0..3 (x4 iters -> 16)
    const int sc4 = (t & 63) * 4;    // staging col 0..252

    float4 px[4], pa;
#pragma unroll
    for (int i = 0; i < 4; ++i)
        px[i] = *(const float4*)(x + ((size_t)(rowb + i * 4 + sp) * DIM + dbase + sc4));
    if (t < 128)
        pa = *(const float4*)(a + ((size_t)(rowb + (t >> 3)) * KCL + (t & 7) * 4));

    float acc[8][4];
#pragma unroll
    for (int i = 0; i < 8; ++i)
#pragma unroll
        for (int j = 0; j < 4; ++j) acc[i][j] = 0.f;

    const int chunks = PP >> 4;      // PP/16
    for (int c = 0; c < chunks; ++c) {
        __syncthreads();
#pragma unroll
        for (int i = 0; i < 4; ++i)
            *(float4*)&xs[(i * 4 + sp) * 256 + sc4] = px[i];
        if (t < 128)
            *(float4*)&as_[(t >> 3) * 32 + (t & 7) * 4] = pa;
        __syncthreads();
        if (c + 1 < chunks) {
            const int p0 = rowb + (c + 1) * 16;
#pragma unroll
            for (int i = 0; i < 4; ++i)
                px[i] = *(const float4*)(x + ((size_t)(p0 + i * 4 + sp) * DIM + dbase + sc4));
            if (t < 128)
                pa = *(const float4*)(a + ((size_t)(p0 + (t >> 3)) * KCL + (t & 7) * 4));
        }
#pragma unroll 4
        for (int p = 0; p < 16; ++p) {
            float4 xA = *(const float4*)&xs[p * 256 + d0];
            float4 xB = *(const float4*)&xs[p * 256 + d0 + 4];
            float4 aA = *(const float4*)&as_[p * 32 + k0];
            float xv[8] = {xA.x, xA.y, xA.z, xA.w, xB.x, xB.y, xB.z, xB.w};
            float av[4] = {aA.x, aA.y, aA.z, aA.w};
#pragma unroll
            for (int i = 0; i < 8; ++i)
#pragma unroll
                for (int j = 0; j < 4; ++j)
                    acc[i][j] = fmaf(xv[i], av[j], acc[i][j]);
        }
    }
    float* vp = vpart + (size_t)ps * BATCH * DIM * KCL;
#pragma unroll
    for (int i = 0; i < 8; ++i)
        *(float4*)(vp + (size_t)(b * DIM + dbase + d0 + i) * KCL + k0) =
            make_float4(acc[i][0], acc[i][1], acc[i][2], acc[i][3]);
}

// ---------------- K4: reduce PS slabs + C*a_sum + intra-normalize ----------
// grid 2048, block 128: 4 rows x 32 k; thread = one (row,k) cell.
__global__ __launch_bounds__(128) void k_norm1(const float* __restrict__ vpart,
                                               const float* __restrict__ a_sum,
                                               const float* __restrict__ Cc,
                                               float* __restrict__ out,
                                               float* __restrict__ ssq, int PS) {
    const int t = threadIdx.x;
    const int row = blockIdx.x * 4 + (t >> 5);   // 0..8191, same b per block
    const int k = t & 31;
    const int b = row >> 9;
    const int d = row & 511;

    float sum = 0.f;
    for (int ps = 0; ps < PS; ++ps)
        sum += vpart[(size_t)ps * BATCH * DIM * KCL + (size_t)row * KCL + k];
    float v = sum + Cc[d * KCL + k] * a_sum[b * KCL + k];

    float ss = v * v;
    ss += __shfl_xor(ss, 1, 32);  ss += __shfl_xor(ss, 2, 32);
    ss += __shfl_xor(ss, 4, 32);  ss += __shfl_xor(ss, 8, 32);
    ss += __shfl_xor(ss, 16, 32);
    float inv = 1.f / fmaxf(sqrtf(ss), 1e-12f);
    float r = v * inv;
    out[(size_t)row * KCL + k] = r;

    float bs = r * r;
    for (int off = 32; off > 0; off >>= 1) bs += __shfl_down(bs, off, 64);
    __shared__ float red[2];
    if ((t & 63) == 0) red[t >> 6] = bs;
    __syncthreads();
    if (t == 0) atomAddF(&ssq[b], red[0] + red[1]);
}

// ---------------- K5: final global L2 normalize ----------------
__global__ __launch_bounds__(256) void k_norm2(float* __restrict__ out,
                                               const float* __restrict__ ssq) {
    const int i4 = blockIdx.x * 256 + threadIdx.x;
    const int b = i4 >> 12;
    float inv = 1.f / fmaxf(sqrtf(ssq[b]), 1e-12f);
    float4 v = *(float4*)(out + (size_t)i4 * 4);
    v.x *= inv; v.y *= inv; v.z *= inv; v.w *= inv;
    *(float4*)(out + (size_t)i4 * 4) = v;
}

extern "C" void kernel_launch(void* const* d_in, const int* in_sizes, int n_in,
                              void* d_out, int out_size, void* d_ws, size_t ws_size,
                              hipStream_t stream) {
    const float* x  = (const float*)d_in[0];
    const float* Wc = (const float*)d_in[1];
    const float* Cc = (const float*)d_in[2];
    float* out = (float*)d_out;

    const size_t A_B  = (size_t)NPOS * KCL * 4;          // 6,422,528
    const size_t SLAB = (size_t)BATCH * DIM * KCL * 4;   // 1,048,576

    // tier ladder: (S d-splits for k_s, PS pos-splits for k_ax)
    int S = 8, PS = 28;
    if (ws_size < A_B + 8 * A_B + 28 * SLAB + 2112) { S = 4; PS = 28; }
    if (ws_size < A_B + 4 * A_B + 28 * SLAB + 2112) { S = 4; PS = 14; }
    if (ws_size < A_B + 4 * A_B + 14 * SLAB + 2112) { S = 2; PS = 7;  }

    char* ws = (char*)d_ws;
    float* a     = (float*)ws;
    float* spart = (float*)(ws + A_B);
    float* vpart = (float*)(ws + A_B + (size_t)S * A_B);
    float* a_sum = (float*)(ws + A_B + (size_t)S * A_B + (size_t)PS * SLAB);
    float* ssq   = (float*)((char*)a_sum + 2048);

    hipMemsetAsync(a_sum, 0, 2048 + 64, stream);

    k_s    <<<dim3(196, S), 256, 0, stream>>>(x, Wc, spart, DIM / S);
    k_soft <<<784, 256, 0, stream>>>(spart, a, a_sum, S);
    k_ax   <<<dim3(PS, 2, BATCH), 256, 0, stream>>>(x, a, vpart, HW / PS);
    k_norm1<<<2048, 128, 0, stream>>>(vpart, a_sum, Cc, out, ssq, PS);
    k_norm2<<<256, 256, 0, stream>>>(out, ssq);
}

// Round 7
// 242.547 us; speedup vs baseline: 1.3247x; 1.3247x over previous
//
#include <hip/hip_runtime.h>
#include <hip/hip_bf16.h>
#include <math.h>

// NetVLAD: B=16, H=W=56 (HW=3136), D=512, K=32, fp32.
// Round 7: k_s rewritten on MFMA bf16. R3/R5/R6 proved the VALU s-GEMM is
// pinned at ~12.6us VALU-busy + ~85% stall by SMEM lgkmcnt(0) full drains
// (Wc scalar operands, 112-SGPR budget) -- invariant to occupancy and
// FMA:scalar ratio. MFMA moves Wc to ds_read_b128. Softmax fused in k_s
// (C-layout is softmax-friendly); spart + k_soft deleted.
// k_ax / k_norm1 / k_norm2 byte-identical to R6 to expose k_ax counters.

#define BATCH 16
#define HW    3136
#define DIM   512
#define KCL   32
#define NPOS  (BATCH * HW)     // 50176

typedef __attribute__((ext_vector_type(8))) short short8;
typedef __attribute__((ext_vector_type(4))) float f32x4;

__device__ __forceinline__ void atomAddF(float* p, float v) {
    unsafeAtomicAdd(p, v);
}

__device__ __forceinline__ unsigned short f2bf(float f) {  // RNE fp32->bf16
    unsigned u = __float_as_uint(f);
    return (unsigned short)((u + 0x7FFFu + ((u >> 16) & 1u)) >> 16);
}

// ---------------- K1: s = x.Wc (MFMA) + softmax -> a, a_sum ----------------
// grid 784, block 256 = 4 waves. Block = 64 flat positions (64|3136 -> b
// uniform). Wave wv owns pos [wv*16, wv*16+16) x all 32 k (2 N-tiles).
// K=512 staged in 4 LDS chunks of 128 d (bf16). WcT (32k x 512d bf16)
// staged once. Frags: A[m=lane&15][k=quad*8+j], B[k=quad*8+j][n=lane&15],
// D[row=quad*4+reg][col=lane&15]  (m89/m120-verified layouts).
#define XS_STR 136   // shorts per pos row: 128 d + 8 pad (16B-aligned rows)
#define WT_STR 520   // shorts per k row:   512 d + 8 pad

__global__ __launch_bounds__(256) void k_s(const float* __restrict__ x,
                                           const float* __restrict__ Wc,
                                           float* __restrict__ a,
                                           float* __restrict__ a_sum) {
    __shared__ unsigned short xs[64 * XS_STR];   // 17408 B
    __shared__ unsigned short wt[32 * WT_STR];   // 33280 B
    __shared__ float asum_l[4][32];
    const int t    = threadIdx.x;
    const int lane = t & 63;
    const int wv   = t >> 6;
    const int l15  = lane & 15;
    const int quad = lane >> 4;
    const int n0   = blockIdx.x * 64;
    const int b    = n0 / HW;          // uniform per block

    // ---- stage WcT[32 k][512 d] bf16, once (visible after first barrier#2)
#pragma unroll
    for (int i = 0; i < 16; ++i) {
        int f  = i * 256 + t;          // 0..4095 float4s of Wc
        int d  = f >> 3;               // 0..511
        int k4 = (f & 7) * 4;
        float4 v = *(const float4*)(Wc + (size_t)d * KCL + k4);
        wt[(k4 + 0) * WT_STR + d] = f2bf(v.x);
        wt[(k4 + 1) * WT_STR + d] = f2bf(v.y);
        wt[(k4 + 2) * WT_STR + d] = f2bf(v.z);
        wt[(k4 + 3) * WT_STR + d] = f2bf(v.w);
    }

    // ---- preload x chunk 0 (64 pos x 128 d fp32 = 8 float4/thread)
    float4 px[8];
#pragma unroll
    for (int i = 0; i < 8; ++i) {
        int f = i * 256 + t;           // pos = f>>5, c4 = (f&31)*4
        px[i] = *(const float4*)(x + ((size_t)(n0 + (f >> 5)) * DIM + (f & 31) * 4));
    }

    f32x4 acc0 = {0.f, 0.f, 0.f, 0.f};
    f32x4 acc1 = {0.f, 0.f, 0.f, 0.f};

    for (int c = 0; c < 4; ++c) {
        __syncthreads();
#pragma unroll
        for (int i = 0; i < 8; ++i) {
            int f = i * 256 + t;
            ushort4 w;
            w.x = f2bf(px[i].x); w.y = f2bf(px[i].y);
            w.z = f2bf(px[i].z); w.w = f2bf(px[i].w);
            *(ushort4*)&xs[(f >> 5) * XS_STR + (f & 31) * 4] = w;
        }
        __syncthreads();
        if (c < 3) {                   // prefetch next d-chunk
            const int dc = (c + 1) * 128;
#pragma unroll
            for (int i = 0; i < 8; ++i) {
                int f = i * 256 + t;
                px[i] = *(const float4*)(x + ((size_t)(n0 + (f >> 5)) * DIM + dc + (f & 31) * 4));
            }
        }
        const int dc = c * 128;
#pragma unroll
        for (int ds = 0; ds < 4; ++ds) {
            const int dloc = ds * 32 + quad * 8;
            short8 af = *(const short8*)&xs[(wv * 16 + l15) * XS_STR + dloc];
            short8 b0 = *(const short8*)&wt[l15 * WT_STR + dc + dloc];
            short8 b1 = *(const short8*)&wt[(16 + l15) * WT_STR + dc + dloc];
            acc0 = __builtin_amdgcn_mfma_f32_16x16x32_bf16(af, b0, acc0, 0, 0, 0);
            acc1 = __builtin_amdgcn_mfma_f32_16x16x32_bf16(af, b1, acc1, 0, 0, 0);
        }
    }

    // ---- softmax over 32 k per position (row = quad*4+reg, col k = l15/ +16)
    float at0 = 0.f, at1 = 0.f;        // per-lane a_sum partials (k=l15, 16+l15)
#pragma unroll
    for (int r = 0; r < 4; ++r) {
        float m = fmaxf(acc0[r], acc1[r]);
        m = fmaxf(m, __shfl_xor(m, 1));
        m = fmaxf(m, __shfl_xor(m, 2));
        m = fmaxf(m, __shfl_xor(m, 4));
        m = fmaxf(m, __shfl_xor(m, 8));
        float e0 = __expf(acc0[r] - m);
        float e1 = __expf(acc1[r] - m);
        float s = e0 + e1;
        s += __shfl_xor(s, 1);
        s += __shfl_xor(s, 2);
        s += __shfl_xor(s, 4);
        s += __shfl_xor(s, 8);
        float inv = 1.f / s;
        float a0 = e0 * inv, a1 = e1 * inv;
        const int pos = n0 + wv * 16 + quad * 4 + r;
        a[(size_t)pos * KCL + l15]      = a0;
        a[(size_t)pos * KCL + 16 + l15] = a1;
        at0 += a0; at1 += a1;
    }
    // reduce a_sum partials over quads (positions), then block-level
    at0 += __shfl_xor(at0, 16); at0 += __shfl_xor(at0, 32);
    at1 += __shfl_xor(at1, 16); at1 += __shfl_xor(at1, 32);
    if (quad == 0) {
        asum_l[wv][l15]      = at0;
        asum_l[wv][16 + l15] = at1;
    }
    __syncthreads();
    if (t < 32)
        atomAddF(&a_sum[b * KCL + t],
                 asum_l[0][t] + asum_l[1][t] + asum_l[2][t] + asum_l[3][t]);
}

// ---------------- K2: ax GEMM, d-split + pos-split (unchanged from R6) ----
// grid (28, 2, 16), block 256. Block (ps, ds, b): 256-d slice, 112 positions
// in chunks of 16. Thread: 8 d x 4 k tile. Reg prefetch.
__global__ __launch_bounds__(256) void k_ax(const float* __restrict__ x,
                                            const float* __restrict__ a,
                                            float* __restrict__ vpart, int PP) {
    __shared__ float xs[16 * 256];   // 16 KB
    __shared__ float as_[16 * 32];   // 2 KB
    const int t  = threadIdx.x;
    const int ps = blockIdx.x;
    const int ds = blockIdx.y;
    const int b  = blockIdx.z;

    const int d0 = (t >> 3) * 8;
    const int k0 = (t & 7) * 4;
    const int dbase = ds * 256;
    const int rowb = b * HW + ps * PP;

    const int sp  = t >> 6;
    const int sc4 = (t & 63) * 4;

    float4 px[4], pa;
#pragma unroll
    for (int i = 0; i < 4; ++i)
        px[i] = *(const float4*)(x + ((size_t)(rowb + i * 4 + sp) * DIM + dbase + sc4));
    if (t < 128)
        pa = *(const float4*)(a + ((size_t)(rowb + (t >> 3)) * KCL + (t & 7) * 4));

    float acc[8][4];
#pragma unroll
    for (int i = 0; i < 8; ++i)
#pragma unroll
        for (int j = 0; j < 4; ++j) acc[i][j] = 0.f;

    const int chunks = PP >> 4;
    for (int c = 0; c < chunks; ++c) {
        __syncthreads();
#pragma unroll
        for (int i = 0; i < 4; ++i)
            *(float4*)&xs[(i * 4 + sp) * 256 + sc4] = px[i];
        if (t < 128)
            *(float4*)&as_[(t >> 3) * 32 + (t & 7) * 4] = pa;
        __syncthreads();
        if (c + 1 < chunks) {
            const int p0 = rowb + (c + 1) * 16;
#pragma unroll
            for (int i = 0; i < 4; ++i)
                px[i] = *(const float4*)(x + ((size_t)(p0 + i * 4 + sp) * DIM + dbase + sc4));
            if (t < 128)
                pa = *(const float4*)(a + ((size_t)(p0 + (t >> 3)) * KCL + (t & 7) * 4));
        }
#pragma unroll 4
        for (int p = 0; p < 16; ++p) {
            float4 xA = *(const float4*)&xs[p * 256 + d0];
            float4 xB = *(const float4*)&xs[p * 256 + d0 + 4];
            float4 aA = *(const float4*)&as_[p * 32 + k0];
            float xv[8] = {xA.x, xA.y, xA.z, xA.w, xB.x, xB.y, xB.z, xB.w};
            float av[4] = {aA.x, aA.y, aA.z, aA.w};
#pragma unroll
            for (int i = 0; i < 8; ++i)
#pragma unroll
                for (int j = 0; j < 4; ++j)
                    acc[i][j] = fmaf(xv[i], av[j], acc[i][j]);
        }
    }
    float* vp = vpart + (size_t)ps * BATCH * DIM * KCL;
#pragma unroll
    for (int i = 0; i < 8; ++i)
        *(float4*)(vp + (size_t)(b * DIM + dbase + d0 + i) * KCL + k0) =
            make_float4(acc[i][0], acc[i][1], acc[i][2], acc[i][3]);
}

// ---------------- K3: reduce PS slabs + C*a_sum + intra-normalize ----------
// grid 2048, block 128: 4 rows x 32 k; thread = one (row,k) cell.
__global__ __launch_bounds__(128) void k_norm1(const float* __restrict__ vpart,
                                               const float* __restrict__ a_sum,
                                               const float* __restrict__ Cc,
                                               float* __restrict__ out,
                                               float* __restrict__ ssq, int PS) {
    const int t = threadIdx.x;
    const int row = blockIdx.x * 4 + (t >> 5);
    const int k = t & 31;
    const int b = row >> 9;
    const int d = row & 511;

    float sum = 0.f;
    for (int ps = 0; ps < PS; ++ps)
        sum += vpart[(size_t)ps * BATCH * DIM * KCL + (size_t)row * KCL + k];
    float v = sum + Cc[d * KCL + k] * a_sum[b * KCL + k];

    float ss = v * v;
    ss += __shfl_xor(ss, 1, 32);  ss += __shfl_xor(ss, 2, 32);
    ss += __shfl_xor(ss, 4, 32);  ss += __shfl_xor(ss, 8, 32);
    ss += __shfl_xor(ss, 16, 32);
    float inv = 1.f / fmaxf(sqrtf(ss), 1e-12f);
    float r = v * inv;
    out[(size_t)row * KCL + k] = r;

    float bs = r * r;
    for (int off = 32; off > 0; off >>= 1) bs += __shfl_down(bs, off, 64);
    __shared__ float red[2];
    if ((t & 63) == 0) red[t >> 6] = bs;
    __syncthreads();
    if (t == 0) atomAddF(&ssq[b], red[0] + red[1]);
}

// ---------------- K4: final global L2 normalize ----------------
__global__ __launch_bounds__(256) void k_norm2(float* __restrict__ out,
                                               const float* __restrict__ ssq) {
    const int i4 = blockIdx.x * 256 + threadIdx.x;
    const int b = i4 >> 12;
    float inv = 1.f / fmaxf(sqrtf(ssq[b]), 1e-12f);
    float4 v = *(float4*)(out + (size_t)i4 * 4);
    v.x *= inv; v.y *= inv; v.z *= inv; v.w *= inv;
    *(float4*)(out + (size_t)i4 * 4) = v;
}

extern "C" void kernel_launch(void* const* d_in, const int* in_sizes, int n_in,
                              void* d_out, int out_size, void* d_ws, size_t ws_size,
                              hipStream_t stream) {
    const float* x  = (const float*)d_in[0];
    const float* Wc = (const float*)d_in[1];
    const float* Cc = (const float*)d_in[2];
    float* out = (float*)d_out;

    // ws: a (6.4 MB) | vpart 28 slabs (28 MB) | a_sum (2 KB) | ssq (64 B)
    const size_t A_B  = (size_t)NPOS * KCL * 4;          // 6,422,528
    const size_t SLAB = (size_t)BATCH * DIM * KCL * 4;   // 1,048,576
    const int PS = 28;

    char* ws = (char*)d_ws;
    float* a     = (float*)ws;
    float* vpart = (float*)(ws + A_B);
    float* a_sum = (float*)(ws + A_B + (size_t)PS * SLAB);
    float* ssq   = (float*)(ws + A_B + (size_t)PS * SLAB + 2048);

    hipMemsetAsync(a_sum, 0, 2048 + 64, stream);

    k_s    <<<784, 256, 0, stream>>>(x, Wc, a, a_sum);
    k_ax   <<<dim3(PS, 2, BATCH), 256, 0, stream>>>(x, a, vpart, HW / PS);
    k_norm1<<<2048, 128, 0, stream>>>(vpart, a_sum, Cc, out, ssq, PS);
    k_norm2<<<256, 256, 0, stream>>>(out, ssq);
}